// Round 1
// baseline (528.858 us; speedup 1.0000x reference)
//
#include <hip/hip_runtime.h>
#include <hip/hip_bf16.h>
#include <math.h>

// Problem: B=32768, n=512, f=30, k=40
//   linear = X @ w1 + b
//   C[i,j] = sum_k v[i, f2f[j], k] * v[j, f2f[i], k]   (symmetric!)
//   inter[b] = sum_{i<j} C[i,j] X[b,i] X[b,j] = X[b]^T W X[b],  W = 0.5*(C - diag(C))
//   out = sigmoid(linear + inter)

#define N_FEAT 512
#define FK 1200      // f*k = 30*40
#define KDIM 40
#define RB 16        // rows per block in main kernel

// ---------------- Kernel 1: build W (512x512 fp32) in workspace ----------------
__global__ __launch_bounds__(256) void ffm_build_w(const float* __restrict__ v,
                                                   const int* __restrict__ f2f,
                                                   float* __restrict__ W) {
    const int j = blockIdx.x * 256 + threadIdx.x;   // 0..511 (gridDim.x == 2)
    const int i = blockIdx.y;                        // 0..511
    const int fi = f2f[i];
    const int fj = f2f[j];
    const float4* a = (const float4*)(v + (size_t)i * FK + (size_t)fj * KDIM);
    const float4* c = (const float4*)(v + (size_t)j * FK + (size_t)fi * KDIM);
    float acc = 0.f;
#pragma unroll
    for (int q = 0; q < KDIM / 4; ++q) {
        float4 av = a[q], cv = c[q];
        acc = fmaf(av.x, cv.x, acc);
        acc = fmaf(av.y, cv.y, acc);
        acc = fmaf(av.z, cv.z, acc);
        acc = fmaf(av.w, cv.w, acc);
    }
    W[(size_t)i * N_FEAT + j] = (i == j) ? 0.f : 0.5f * acc;
}

// ---------------- Kernel 2: fused quadratic form + linear + sigmoid ----------------
// One block of 256 threads handles RB=16 rows of X.
// Thread t owns output columns j0=t, j1=t+256; accumulates y[j] = sum_i W[j][i] * x[i]
// (W symmetric, so W[j][i] rows are contiguous float4 loads).
__global__ __launch_bounds__(256) void ffm_main(const float* __restrict__ X,
                                                const float* __restrict__ w1,
                                                const float* __restrict__ bvec,
                                                const float* __restrict__ W,
                                                float* __restrict__ out) {
    __shared__ float xs[RB][N_FEAT];    // 32 KB
    __shared__ float red[4][RB];

    const int tid = threadIdx.x;
    const size_t row0 = (size_t)blockIdx.x * RB;

    // Stage X tile (RB*512 floats = 2048 float4s; 8 per thread, coalesced).
    {
        const float4* Xv = (const float4*)(X + row0 * N_FEAT);
        float4* xsv = (float4*)&xs[0][0];
#pragma unroll
        for (int it = 0; it < (RB * (N_FEAT / 4)) / 256; ++it)
            xsv[it * 256 + tid] = Xv[it * 256 + tid];
    }
    __syncthreads();

    const int j0 = tid;
    const int j1 = tid + 256;

    float y0[RB], y1[RB];
#pragma unroll
    for (int r = 0; r < RB; ++r) { y0[r] = 0.f; y1[r] = 0.f; }

    const float4* Wa = (const float4*)(W + (size_t)j0 * N_FEAT);
    const float4* Wb = (const float4*)(W + (size_t)j1 * N_FEAT);

    for (int i4 = 0; i4 < N_FEAT / 4; ++i4) {
        float4 wa = Wa[i4];
        float4 wb = Wb[i4];
#pragma unroll
        for (int r = 0; r < RB; ++r) {
            float4 xv = *(const float4*)(&xs[r][i4 * 4]);   // same addr across threads: broadcast
            y0[r] = fmaf(xv.x, wa.x, y0[r]);
            y0[r] = fmaf(xv.y, wa.y, y0[r]);
            y0[r] = fmaf(xv.z, wa.z, y0[r]);
            y0[r] = fmaf(xv.w, wa.w, y0[r]);
            y1[r] = fmaf(xv.x, wb.x, y1[r]);
            y1[r] = fmaf(xv.y, wb.y, y1[r]);
            y1[r] = fmaf(xv.z, wb.z, y1[r]);
            y1[r] = fmaf(xv.w, wb.w, y1[r]);
        }
    }

    // Epilogue: s[r] = sum_j x[r][j]*(y[j] + w1[j]); reduce over threads; + b; sigmoid.
    const float w10 = w1[j0];
    const float w11 = w1[j1];
    const int lane = tid & 63;
    const int wid  = tid >> 6;
#pragma unroll
    for (int r = 0; r < RB; ++r) {
        float sr = xs[r][j0] * (y0[r] + w10) + xs[r][j1] * (y1[r] + w11);
#pragma unroll
        for (int off = 32; off > 0; off >>= 1)
            sr += __shfl_down(sr, off, 64);
        if (lane == 0) red[wid][r] = sr;
    }
    __syncthreads();
    if (tid < RB) {
        float t = red[0][tid] + red[1][tid] + red[2][tid] + red[3][tid] + bvec[0];
        out[row0 + tid] = 1.0f / (1.0f + expf(-t));
    }
}

extern "C" void kernel_launch(void* const* d_in, const int* in_sizes, int n_in,
                              void* d_out, int out_size, void* d_ws, size_t ws_size,
                              hipStream_t stream) {
    const float* X   = (const float*)d_in[0];   // 32768 x 512
    const float* w1  = (const float*)d_in[1];   // 512 x 1
    const float* b   = (const float*)d_in[2];   // 1
    const float* v   = (const float*)d_in[3];   // 512 x 30 x 40
    const int*   f2f = (const int*)d_in[4];     // 512
    float* out = (float*)d_out;                 // 32768

    float* W = (float*)d_ws;                    // 512*512*4 = 1 MB scratch

    const int B = in_sizes[0] / N_FEAT;         // 32768

    ffm_build_w<<<dim3(2, N_FEAT), 256, 0, stream>>>(v, f2f, W);
    ffm_main<<<B / RB, 256, 0, stream>>>(X, w1, b, W, out);
}

// Round 2
// 148.993 us; speedup vs baseline: 3.5496x; 3.5496x over previous
//
#include <hip/hip_runtime.h>
#include <hip/hip_bf16.h>
#include <math.h>

// FFM: B=32768, n=512, f=30, k=40
// inter[b] = X[b]^T W X[b],  W = 0.5*(C - diag(C)), C symmetric
// out = sigmoid(X@w1 + b + inter)
//
// Plan: Y = Xbf16 @ W16 via MFMA (W symmetric -> B^T layout free), fused
// epilogue logit partial = sum_j x_j*(y_j + w1_j) per 128-col block.

#define N_FEAT 512
#define FK 1200
#define KDIM 40
#define B_ROWS 32768
#define BM 128
#define BN 128
#define BK 64

typedef __attribute__((ext_vector_type(8))) short short8;
typedef __attribute__((ext_vector_type(4))) float f32x4;

__device__ __forceinline__ unsigned short bf16_rne(float f) {
    union { float f; unsigned int u; } c; c.f = f;
    unsigned int u = c.u;
    u += 0x7fffu + ((u >> 16) & 1u);
    return (unsigned short)(u >> 16);
}

__device__ __forceinline__ void async_copy16(const void* g, void* l) {
    __builtin_amdgcn_global_load_lds(
        (const __attribute__((address_space(1))) void*)g,
        (__attribute__((address_space(3))) void*)l,
        16, 0, 0);
}

// ---------------- Kernel 0: X fp32 -> bf16 ----------------
__global__ __launch_bounds__(256) void cvt_x(const float* __restrict__ X,
                                             unsigned short* __restrict__ Xb) {
    const int i = blockIdx.x * 256 + threadIdx.x;     // indexes float4 groups
    f32x4 x = ((const f32x4*)X)[i];
    ushort4 o;
    o.x = bf16_rne(x.x);
    o.y = bf16_rne(x.y);
    o.z = bf16_rne(x.z);
    o.w = bf16_rne(x.w);
    ((ushort4*)Xb)[i] = o;
}

// ---------------- Kernel 1: build W16 (512x512 bf16) ----------------
__global__ __launch_bounds__(256) void build_w16(const float* __restrict__ v,
                                                 const int* __restrict__ f2f,
                                                 unsigned short* __restrict__ W16) {
    const int j = blockIdx.x * 256 + threadIdx.x;   // 0..511
    const int i = blockIdx.y;                        // 0..511
    const int fi = f2f[i];
    const int fj = f2f[j];
    const float4* a = (const float4*)(v + (size_t)i * FK + (size_t)fj * KDIM);
    const float4* c = (const float4*)(v + (size_t)j * FK + (size_t)fi * KDIM);
    float acc = 0.f;
#pragma unroll
    for (int q = 0; q < KDIM / 4; ++q) {
        float4 av = a[q], cv = c[q];
        acc = fmaf(av.x, cv.x, acc);
        acc = fmaf(av.y, cv.y, acc);
        acc = fmaf(av.z, cv.z, acc);
        acc = fmaf(av.w, cv.w, acc);
    }
    W16[(size_t)i * N_FEAT + j] = (i == j) ? (unsigned short)0 : bf16_rne(0.5f * acc);
}

// ---------------- Kernel 2: MFMA GEMM + fused epilogue ----------------
// grid: (4 col-blocks, 256 row-blocks), 256 threads (4 waves).
// Wave w: wm=w&1 (row half), wn=w>>1 (col half); 4x4 grid of 16x16x32 MFMAs.
__global__ __launch_bounds__(256) void ffm_mfma(const unsigned short* __restrict__ Xb,
                                                const unsigned short* __restrict__ W16,
                                                const float* __restrict__ X,
                                                const float* __restrict__ w1,
                                                float* __restrict__ pOut) {
    __shared__ unsigned short As[BM * BK];   // 16 KB, row-major [128][64]
    __shared__ unsigned short Bs[BN * BK];   // 16 KB
    __shared__ float part[2][BM];            // per-wn row partials

    const int tid  = threadIdx.x;
    const int lane = tid & 63;
    const int wave = tid >> 6;
    const int wm = wave & 1;
    const int wn = wave >> 1;
    const int quad = lane >> 4;
    const int l16  = lane & 15;

    const int cb   = blockIdx.x;                 // col block 0..3
    const int col0 = cb * BN;
    const size_t row0 = (size_t)blockIdx.y * BM;

    f32x4 acc[4][4];
#pragma unroll
    for (int mi = 0; mi < 4; ++mi)
#pragma unroll
        for (int ni = 0; ni < 4; ++ni)
            acc[mi][ni] = (f32x4){0.f, 0.f, 0.f, 0.f};

    // staging source coords for this lane within a 1 KB chunk (8 rows x 128 B)
    const int srow = lane >> 3;          // 0..7
    const int scol = (lane & 7) * 8;     // bf16 elems, 16 B per lane

    for (int k0 = 0; k0 < N_FEAT; k0 += BK) {
#pragma unroll
        for (int c = 0; c < 4; ++c) {
            const int chunk = wave * 4 + c;              // 0..15
            const int r = chunk * 8 + srow;
            async_copy16(Xb  + (row0 + r) * N_FEAT + k0 + scol, As + chunk * 512);
            async_copy16(W16 + (size_t)(col0 + r) * N_FEAT + k0 + scol, Bs + chunk * 512);
        }
        __syncthreads();   // drains vmcnt for global_load_lds

#pragma unroll
        for (int kk = 0; kk < 2; ++kk) {
            short8 a[4], b[4];
#pragma unroll
            for (int mi = 0; mi < 4; ++mi) {
                const int ar = wm * 64 + mi * 16 + l16;
                a[mi] = *(const short8*)(As + ar * BK + kk * 32 + quad * 8);
            }
#pragma unroll
            for (int ni = 0; ni < 4; ++ni) {
                const int br = wn * 64 + ni * 16 + l16;
                b[ni] = *(const short8*)(Bs + br * BK + kk * 32 + quad * 8);
            }
#pragma unroll
            for (int mi = 0; mi < 4; ++mi)
#pragma unroll
                for (int ni = 0; ni < 4; ++ni)
                    acc[mi][ni] = __builtin_amdgcn_mfma_f32_16x16x32_bf16(
                        a[mi], b[ni], acc[mi][ni], 0, 0, 0);
        }
        __syncthreads();   // protect LDS reuse
    }

    // Epilogue: partial[row] = sum_{j in colblock} X[row][j]*(Y[row][j] + w1[j])
    // Lane holds Y at (row = quad*4+reg, col = l16) per 16x16 tile.
#pragma unroll
    for (int mi = 0; mi < 4; ++mi) {
        float rs[4] = {0.f, 0.f, 0.f, 0.f};
        const size_t growb = row0 + wm * 64 + mi * 16 + quad * 4;
#pragma unroll
        for (int ni = 0; ni < 4; ++ni) {
            const int gcol = col0 + wn * 64 + ni * 16 + l16;
            const float w1v = w1[gcol];
#pragma unroll
            for (int reg = 0; reg < 4; ++reg) {
                const float xv = X[(growb + reg) * N_FEAT + gcol];
                rs[reg] += xv * (acc[mi][ni][reg] + w1v);
            }
        }
#pragma unroll
        for (int off = 1; off < 16; off <<= 1)
#pragma unroll
            for (int reg = 0; reg < 4; ++reg)
                rs[reg] += __shfl_xor(rs[reg], off, 16);
        if (l16 == 0) {
            const int lrow = wm * 64 + mi * 16 + quad * 4;
#pragma unroll
            for (int reg = 0; reg < 4; ++reg)
                part[wn][lrow + reg] = rs[reg];
        }
    }
    __syncthreads();

    if (tid < BM) {
        pOut[(size_t)cb * B_ROWS + row0 + tid] = part[0][tid] + part[1][tid];
    }
}

// ---------------- Kernel 3: sum partials + linear bias + sigmoid ----------------
__global__ __launch_bounds__(256) void ffm_final(const float* __restrict__ p,
                                                 const float* __restrict__ bvec,
                                                 float* __restrict__ out) {
    const int i = blockIdx.x * 256 + threadIdx.x;
    const float t = p[i] + p[B_ROWS + i] + p[2 * B_ROWS + i] + p[3 * B_ROWS + i] + bvec[0];
    out[i] = 1.0f / (1.0f + expf(-t));
}

extern "C" void kernel_launch(void* const* d_in, const int* in_sizes, int n_in,
                              void* d_out, int out_size, void* d_ws, size_t ws_size,
                              hipStream_t stream) {
    const float* X   = (const float*)d_in[0];   // 32768 x 512
    const float* w1  = (const float*)d_in[1];   // 512
    const float* b   = (const float*)d_in[2];   // 1
    const float* v   = (const float*)d_in[3];   // 512 x 30 x 40
    const int*   f2f = (const int*)d_in[4];     // 512
    float* out = (float*)d_out;                 // 32768

    // workspace layout
    unsigned short* W16 = (unsigned short*)d_ws;                         // 512 KB
    unsigned short* Xb  = (unsigned short*)((char*)d_ws + (1u << 20));   // 32 MB
    float*          pP  = (float*)((char*)d_ws + (1u << 20) + (32u << 20)); // 512 KB

    cvt_x<<<(B_ROWS * N_FEAT / 4) / 256, 256, 0, stream>>>(X, Xb);
    build_w16<<<dim3(2, N_FEAT), 256, 0, stream>>>(v, f2f, W16);
    ffm_mfma<<<dim3(4, B_ROWS / BM), 256, 0, stream>>>(Xb, W16, X, w1, pP);
    ffm_final<<<B_ROWS / 256, 256, 0, stream>>>(pP, b, out);
}

// Round 3
// 146.827 us; speedup vs baseline: 3.6019x; 1.0148x over previous
//
#include <hip/hip_runtime.h>
#include <hip/hip_bf16.h>
#include <math.h>

// FFM: B=32768, n=512, f=30, k=40
// inter[b] = X[b]^T W X[b],  W = 0.5*(C - diag(C)), C symmetric
// out = sigmoid(X@w1 + b + inter)
//
// Y = Xbf16 @ W16 via MFMA (W symmetric -> B^T layout free), fused epilogue
// partial = sum_j x_j*(y_j + w1_j) per 128-col block.
// R3 change: XOR-swizzled LDS chunk layout (chunk (r,c) stored at c^(r&7))
// to kill the stride-128B 16-lane bank conflict on a/b fragment ds_reads.

#define N_FEAT 512
#define FK 1200
#define KDIM 40
#define B_ROWS 32768
#define BM 128
#define BN 128
#define BK 64

typedef __attribute__((ext_vector_type(8))) short short8;
typedef __attribute__((ext_vector_type(4))) float f32x4;

__device__ __forceinline__ unsigned short bf16_rne(float f) {
    union { float f; unsigned int u; } c; c.f = f;
    unsigned int u = c.u;
    u += 0x7fffu + ((u >> 16) & 1u);
    return (unsigned short)(u >> 16);
}

__device__ __forceinline__ void async_copy16(const void* g, void* l) {
    __builtin_amdgcn_global_load_lds(
        (const __attribute__((address_space(1))) void*)g,
        (__attribute__((address_space(3))) void*)l,
        16, 0, 0);
}

// ---------------- Kernel 0: X fp32 -> bf16 ----------------
__global__ __launch_bounds__(256) void cvt_x(const float* __restrict__ X,
                                             unsigned short* __restrict__ Xb) {
    const int i = blockIdx.x * 256 + threadIdx.x;
    f32x4 x = ((const f32x4*)X)[i];
    ushort4 o;
    o.x = bf16_rne(x.x);
    o.y = bf16_rne(x.y);
    o.z = bf16_rne(x.z);
    o.w = bf16_rne(x.w);
    ((ushort4*)Xb)[i] = o;
}

// ---------------- Kernel 1: build W16 (512x512 bf16) ----------------
__global__ __launch_bounds__(256) void build_w16(const float* __restrict__ v,
                                                 const int* __restrict__ f2f,
                                                 unsigned short* __restrict__ W16) {
    const int j = blockIdx.x * 256 + threadIdx.x;
    const int i = blockIdx.y;
    const int fi = f2f[i];
    const int fj = f2f[j];
    const float4* a = (const float4*)(v + (size_t)i * FK + (size_t)fj * KDIM);
    const float4* c = (const float4*)(v + (size_t)j * FK + (size_t)fi * KDIM);
    float acc = 0.f;
#pragma unroll
    for (int q = 0; q < KDIM / 4; ++q) {
        float4 av = a[q], cv = c[q];
        acc = fmaf(av.x, cv.x, acc);
        acc = fmaf(av.y, cv.y, acc);
        acc = fmaf(av.z, cv.z, acc);
        acc = fmaf(av.w, cv.w, acc);
    }
    W16[(size_t)i * N_FEAT + j] = (i == j) ? (unsigned short)0 : bf16_rne(0.5f * acc);
}

// ---------------- Kernel 2: MFMA GEMM + fused epilogue ----------------
// grid: (4 col-blocks, 256 row-blocks), 256 threads (4 waves).
// LDS tiles use XOR-swizzled 16B-chunk layout: chunk (r,c) at (r, c^(r&7)).
__global__ __launch_bounds__(256) void ffm_mfma(const unsigned short* __restrict__ Xb,
                                                const unsigned short* __restrict__ W16,
                                                const float* __restrict__ X,
                                                const float* __restrict__ w1,
                                                float* __restrict__ pOut) {
    __shared__ unsigned short As[BM * BK];   // 16 KB
    __shared__ unsigned short Bs[BN * BK];   // 16 KB
    __shared__ float part[2][BM];

    const int tid  = threadIdx.x;
    const int lane = tid & 63;
    const int wave = tid >> 6;
    const int wm = wave & 1;
    const int wn = wave >> 1;
    const int quad = lane >> 4;
    const int l16  = lane & 15;

    const int cb   = blockIdx.x;
    const int col0 = cb * BN;
    const size_t row0 = (size_t)blockIdx.y * BM;

    f32x4 acc[4][4];
#pragma unroll
    for (int mi = 0; mi < 4; ++mi)
#pragma unroll
        for (int ni = 0; ni < 4; ++ni)
            acc[mi][ni] = (f32x4){0.f, 0.f, 0.f, 0.f};

    // staging source coords: wave-instruction stages 1 KB = 8 rows x 8 chunks.
    // LDS dest is contiguous (base + lane*16); global source chunk is the
    // XOR-swizzle preimage: c = (lane&7) ^ (srow&7).
    const int srow = lane >> 3;                         // 0..7
    const int scol = (((lane & 7) ^ (srow & 7)) * 8);   // bf16 elems

    const int aswz = l16 & 7;                           // row-derived XOR for frag reads

    for (int k0 = 0; k0 < N_FEAT; k0 += BK) {
#pragma unroll
        for (int c = 0; c < 4; ++c) {
            const int chunk = wave * 4 + c;              // 0..15 (8 rows each)
            const int r = chunk * 8 + srow;
            async_copy16(Xb  + (row0 + r) * N_FEAT + k0 + scol, As + chunk * 512);
            async_copy16(W16 + (size_t)(col0 + r) * N_FEAT + k0 + scol, Bs + chunk * 512);
        }
        __syncthreads();

#pragma unroll
        for (int kk = 0; kk < 2; ++kk) {
            short8 a[4], b[4];
            const int kc = kk * 4 + quad;                // chunk index 0..7
            const int swc = (kc ^ aswz) * 8;             // swizzled elem offset
#pragma unroll
            for (int mi = 0; mi < 4; ++mi) {
                const int ar = wm * 64 + mi * 16 + l16;
                a[mi] = *(const short8*)(As + ar * BK + swc);
            }
#pragma unroll
            for (int ni = 0; ni < 4; ++ni) {
                const int br = wn * 64 + ni * 16 + l16;
                b[ni] = *(const short8*)(Bs + br * BK + swc);
            }
#pragma unroll
            for (int mi = 0; mi < 4; ++mi)
#pragma unroll
                for (int ni = 0; ni < 4; ++ni)
                    acc[mi][ni] = __builtin_amdgcn_mfma_f32_16x16x32_bf16(
                        a[mi], b[ni], acc[mi][ni], 0, 0, 0);
        }
        __syncthreads();
    }

    // Epilogue: partial[row] = sum_{j in colblock} X[row][j]*(Y[row][j] + w1[j])
#pragma unroll
    for (int mi = 0; mi < 4; ++mi) {
        float rs[4] = {0.f, 0.f, 0.f, 0.f};
        const size_t growb = row0 + wm * 64 + mi * 16 + quad * 4;
#pragma unroll
        for (int ni = 0; ni < 4; ++ni) {
            const int gcol = col0 + wn * 64 + ni * 16 + l16;
            const float w1v = w1[gcol];
#pragma unroll
            for (int reg = 0; reg < 4; ++reg) {
                const float xv = X[(growb + reg) * N_FEAT + gcol];
                rs[reg] += xv * (acc[mi][ni][reg] + w1v);
            }
        }
#pragma unroll
        for (int off = 1; off < 16; off <<= 1)
#pragma unroll
            for (int reg = 0; reg < 4; ++reg)
                rs[reg] += __shfl_xor(rs[reg], off, 16);
        if (l16 == 0) {
            const int lrow = wm * 64 + mi * 16 + quad * 4;
#pragma unroll
            for (int reg = 0; reg < 4; ++reg)
                part[wn][lrow + reg] = rs[reg];
        }
    }
    __syncthreads();

    if (tid < BM) {
        pOut[(size_t)cb * B_ROWS + row0 + tid] = part[0][tid] + part[1][tid];
    }
}

// ---------------- Kernel 3: sum partials + linear bias + sigmoid ----------------
__global__ __launch_bounds__(256) void ffm_final(const float* __restrict__ p,
                                                 const float* __restrict__ bvec,
                                                 float* __restrict__ out) {
    const int i = blockIdx.x * 256 + threadIdx.x;
    const float t = p[i] + p[B_ROWS + i] + p[2 * B_ROWS + i] + p[3 * B_ROWS + i] + bvec[0];
    out[i] = 1.0f / (1.0f + expf(-t));
}

extern "C" void kernel_launch(void* const* d_in, const int* in_sizes, int n_in,
                              void* d_out, int out_size, void* d_ws, size_t ws_size,
                              hipStream_t stream) {
    const float* X   = (const float*)d_in[0];
    const float* w1  = (const float*)d_in[1];
    const float* b   = (const float*)d_in[2];
    const float* v   = (const float*)d_in[3];
    const int*   f2f = (const int*)d_in[4];
    float* out = (float*)d_out;

    unsigned short* W16 = (unsigned short*)d_ws;                            // 512 KB
    unsigned short* Xb  = (unsigned short*)((char*)d_ws + (1u << 20));      // 32 MB
    float*          pP  = (float*)((char*)d_ws + (1u << 20) + (32u << 20)); // 512 KB

    cvt_x<<<(B_ROWS * N_FEAT / 4) / 256, 256, 0, stream>>>(X, Xb);
    build_w16<<<dim3(2, N_FEAT), 256, 0, stream>>>(v, f2f, W16);
    ffm_mfma<<<dim3(4, B_ROWS / BM), 256, 0, stream>>>(Xb, W16, X, w1, pP);
    ffm_final<<<B_ROWS / 256, 256, 0, stream>>>(pP, b, out);
}

// Round 4
// 133.913 us; speedup vs baseline: 3.9493x; 1.0964x over previous
//
#include <hip/hip_runtime.h>
#include <hip/hip_bf16.h>
#include <math.h>

// FFM: B=32768, n=512, f=30, k=40
// inter[b] = X[b]^T W X[b],  W = 0.5*(C - diag(C)), C symmetric
// out = sigmoid(X@w1 + b + inter)
//
// R4: single fused GEMM kernel. Each block (1/CU) stages bf16(X) 128x512
// fully resident in LDS (130 KB, padded rows), loops 4 col-blocks x 8
// k-slices streaming W16 tiles via global_load_lds. Epilogue partials
// accumulate in registers across col-blocks; sigmoid written directly.
// X read exactly once from HBM (64 MB). cvt_x / Xb / pOut / final removed.

#define N_FEAT 512
#define FK 1200
#define KDIM 40
#define B_ROWS 32768
#define BM 128
#define BK 64
#define APAD 520   // As row stride (elems): 1040 B -> 16B-aligned, +4 banks/row

typedef __attribute__((ext_vector_type(8))) short short8;
typedef __attribute__((ext_vector_type(4))) float f32x4;

__device__ __forceinline__ unsigned short bf16_rne(float f) {
    union { float f; unsigned int u; } c; c.f = f;
    unsigned int u = c.u;
    u += 0x7fffu + ((u >> 16) & 1u);
    return (unsigned short)(u >> 16);
}

__device__ __forceinline__ float bf16_to_f(unsigned short h) {
    union { unsigned int u; float f; } c;
    c.u = ((unsigned int)h) << 16;
    return c.f;
}

__device__ __forceinline__ void async_copy16(const void* g, void* l) {
    __builtin_amdgcn_global_load_lds(
        (const __attribute__((address_space(1))) void*)g,
        (__attribute__((address_space(3))) void*)l,
        16, 0, 0);
}

// ---------------- Kernel 1: build W16 (512x512 bf16) ----------------
__global__ __launch_bounds__(256) void build_w16(const float* __restrict__ v,
                                                 const int* __restrict__ f2f,
                                                 unsigned short* __restrict__ W16) {
    const int j = blockIdx.x * 256 + threadIdx.x;
    const int i = blockIdx.y;
    const int fi = f2f[i];
    const int fj = f2f[j];
    const float4* a = (const float4*)(v + (size_t)i * FK + (size_t)fj * KDIM);
    const float4* c = (const float4*)(v + (size_t)j * FK + (size_t)fi * KDIM);
    float acc = 0.f;
#pragma unroll
    for (int q = 0; q < KDIM / 4; ++q) {
        float4 av = a[q], cv = c[q];
        acc = fmaf(av.x, cv.x, acc);
        acc = fmaf(av.y, cv.y, acc);
        acc = fmaf(av.z, cv.z, acc);
        acc = fmaf(av.w, cv.w, acc);
    }
    W16[(size_t)i * N_FEAT + j] = (i == j) ? (unsigned short)0 : bf16_rne(0.5f * acc);
}

// ---------------- Kernel 2: fused GEMM + quadratic-form epilogue ----------------
// grid: 256 blocks x 256 threads (4 waves). Wave w: wm=w&1 rows, wn=w>>1 cols.
__global__ __launch_bounds__(256, 1) void ffm_fused(const float* __restrict__ X,
                                                    const unsigned short* __restrict__ W16,
                                                    const float* __restrict__ w1,
                                                    const float* __restrict__ bvec,
                                                    float* __restrict__ out) {
    __shared__ __align__(16) unsigned short As[BM * APAD];  // 130 KB, full-K X tile
    __shared__ __align__(16) unsigned short Bs[128 * BK];   // 16 KB, W16 tile
    __shared__ float part[2][BM];

    const int tid  = threadIdx.x;
    const int lane = tid & 63;
    const int wave = tid >> 6;
    const int wm = wave & 1;
    const int wn = wave >> 1;
    const int quad = lane >> 4;
    const int l16  = lane & 15;

    const size_t row0 = (size_t)blockIdx.x * BM;

    // ---- Phase A: stage As = bf16(X[row0 : row0+128][0:512]) ----
    // chunk g (0..8191): row r = g>>6, chunk-in-row cc = g&63 (8 bf16 = 32 B fp32 src).
    // Lane-consecutive cc -> fully contiguous 2 KB per wave-instruction.
    {
        const float4* X4 = (const float4*)(X + row0 * N_FEAT);
        for (int u = 0; u < 32; ++u) {
            const int g  = u * 256 + tid;
            const int r  = g >> 6;
            const int cc = g & 63;
            float4 f0 = X4[r * 128 + cc * 2];
            float4 f1 = X4[r * 128 + cc * 2 + 1];
            union { unsigned short us[8]; short8 v; } pk;
            pk.us[0] = bf16_rne(f0.x);
            pk.us[1] = bf16_rne(f0.y);
            pk.us[2] = bf16_rne(f0.z);
            pk.us[3] = bf16_rne(f0.w);
            pk.us[4] = bf16_rne(f1.x);
            pk.us[5] = bf16_rne(f1.y);
            pk.us[6] = bf16_rne(f1.z);
            pk.us[7] = bf16_rne(f1.w);
            *(short8*)(As + r * APAD + cc * 8) = pk.v;
        }
    }

    // Bs staging coords (XOR preimage so LDS dest stays lane-contiguous).
    const int srow = lane >> 3;                      // 0..7
    const int scol = (((lane & 7) ^ srow) * 8);      // source chunk elems
    const int aswz = l16 & 7;                        // read-side XOR

    float rs[4][4];                                  // [mi][reg] logit partials
#pragma unroll
    for (int mi = 0; mi < 4; ++mi)
#pragma unroll
        for (int reg = 0; reg < 4; ++reg) rs[mi][reg] = 0.f;

    for (int cb = 0; cb < 4; ++cb) {
        const int col0 = cb * 128;

        f32x4 acc[4][4];
#pragma unroll
        for (int mi = 0; mi < 4; ++mi)
#pragma unroll
            for (int ni = 0; ni < 4; ++ni)
                acc[mi][ni] = (f32x4){0.f, 0.f, 0.f, 0.f};

        for (int k0 = 0; k0 < N_FEAT; k0 += BK) {
            __syncthreads();   // Bs safe to overwrite (prior readers done)
#pragma unroll
            for (int c = 0; c < 4; ++c) {
                const int chunk = wave * 4 + c;          // 0..15, 1 KB each
                const int r = chunk * 8 + srow;
                async_copy16(W16 + (size_t)(col0 + r) * N_FEAT + k0 + scol,
                             Bs + chunk * 512);
            }
            __syncthreads();   // drain staging (covers Phase A writes on iter 0)

#pragma unroll
            for (int kk = 0; kk < 2; ++kk) {
                short8 a[4], b[4];
#pragma unroll
                for (int mi = 0; mi < 4; ++mi) {
                    const int ar = wm * 64 + mi * 16 + l16;
                    a[mi] = *(const short8*)(As + ar * APAD + k0 + kk * 32 + quad * 8);
                }
                const int swc = ((kk * 4 + quad) ^ aswz) * 8;
#pragma unroll
                for (int ni = 0; ni < 4; ++ni) {
                    const int br = wn * 64 + ni * 16 + l16;
                    b[ni] = *(const short8*)(Bs + br * BK + swc);
                }
#pragma unroll
                for (int mi = 0; mi < 4; ++mi)
#pragma unroll
                    for (int ni = 0; ni < 4; ++ni)
                        acc[mi][ni] = __builtin_amdgcn_mfma_f32_16x16x32_bf16(
                            a[mi], b[ni], acc[mi][ni], 0, 0, 0);
            }
        }

        // Epilogue for this col-block: rs += x_hat * (y + w1), x_hat from As.
        float w1v[4];
#pragma unroll
        for (int ni = 0; ni < 4; ++ni)
            w1v[ni] = w1[col0 + wn * 64 + ni * 16 + l16];
#pragma unroll
        for (int mi = 0; mi < 4; ++mi) {
#pragma unroll
            for (int ni = 0; ni < 4; ++ni) {
                const int gc = col0 + wn * 64 + ni * 16 + l16;
#pragma unroll
                for (int reg = 0; reg < 4; ++reg) {
                    const int row = wm * 64 + mi * 16 + quad * 4 + reg;
                    const float xf = bf16_to_f(As[row * APAD + gc]);
                    rs[mi][reg] = fmaf(xf, acc[mi][ni][reg] + w1v[ni], rs[mi][reg]);
                }
            }
        }
    }

    // Reduce over l16 (within quad), combine wn halves, bias + sigmoid.
#pragma unroll
    for (int mi = 0; mi < 4; ++mi)
#pragma unroll
        for (int reg = 0; reg < 4; ++reg) {
            float r = rs[mi][reg];
#pragma unroll
            for (int off = 1; off < 16; off <<= 1)
                r += __shfl_xor(r, off, 16);
            if (l16 == 0)
                part[wn][wm * 64 + mi * 16 + quad * 4 + reg] = r;
        }
    __syncthreads();

    if (tid < BM) {
        const float t = part[0][tid] + part[1][tid] + bvec[0];
        out[row0 + tid] = 1.0f / (1.0f + expf(-t));
    }
}

extern "C" void kernel_launch(void* const* d_in, const int* in_sizes, int n_in,
                              void* d_out, int out_size, void* d_ws, size_t ws_size,
                              hipStream_t stream) {
    const float* X   = (const float*)d_in[0];   // 32768 x 512
    const float* w1  = (const float*)d_in[1];   // 512
    const float* b   = (const float*)d_in[2];   // 1
    const float* v   = (const float*)d_in[3];   // 512 x 30 x 40
    const int*   f2f = (const int*)d_in[4];     // 512
    float* out = (float*)d_out;                 // 32768

    unsigned short* W16 = (unsigned short*)d_ws;   // 512 KB scratch

    build_w16<<<dim3(2, N_FEAT), 256, 0, stream>>>(v, f2f, W16);
    ffm_fused<<<B_ROWS / BM, 256, 0, stream>>>(X, W16, w1, b, out);
}

// Round 5
// 126.307 us; speedup vs baseline: 4.1871x; 1.0602x over previous
//
#include <hip/hip_runtime.h>
#include <hip/hip_bf16.h>
#include <math.h>

// FFM: B=32768, n=512, f=30, k=40
// inter[b] = X[b]^T W X[b],  W = 0.5*(C - diag(C)), C symmetric
// out = sigmoid(X@w1 + b + inter)
//
// R5: occupancy fix. BM=64 rows/block, As = 64x512 bf16 XOR-swizzled
// (unpadded, 64 KB), Bs 16 KB single-buffered, part[] aliases dead Bs.
// 80 KB LDS -> 2 blocks/CU, 8 waves/CU (was 1x4). Grid 512 blocks.

#define N_FEAT 512
#define FK 1200
#define KDIM 40
#define B_ROWS 32768
#define BM 64
#define BK 64

typedef __attribute__((ext_vector_type(8))) short short8;
typedef __attribute__((ext_vector_type(4))) float f32x4;

__device__ __forceinline__ unsigned short bf16_rne(float f) {
    union { float f; unsigned int u; } c; c.f = f;
    unsigned int u = c.u;
    u += 0x7fffu + ((u >> 16) & 1u);
    return (unsigned short)(u >> 16);
}

__device__ __forceinline__ float bf16_to_f(unsigned short h) {
    union { unsigned int u; float f; } c;
    c.u = ((unsigned int)h) << 16;
    return c.f;
}

__device__ __forceinline__ void async_copy16(const void* g, void* l) {
    __builtin_amdgcn_global_load_lds(
        (const __attribute__((address_space(1))) void*)g,
        (__attribute__((address_space(3))) void*)l,
        16, 0, 0);
}

// ---------------- Kernel 1: build W16 (512x512 bf16) ----------------
__global__ __launch_bounds__(256) void build_w16(const float* __restrict__ v,
                                                 const int* __restrict__ f2f,
                                                 unsigned short* __restrict__ W16) {
    const int j = blockIdx.x * 256 + threadIdx.x;
    const int i = blockIdx.y;
    const int fi = f2f[i];
    const int fj = f2f[j];
    const float4* a = (const float4*)(v + (size_t)i * FK + (size_t)fj * KDIM);
    const float4* c = (const float4*)(v + (size_t)j * FK + (size_t)fi * KDIM);
    float acc = 0.f;
#pragma unroll
    for (int q = 0; q < KDIM / 4; ++q) {
        float4 av = a[q], cv = c[q];
        acc = fmaf(av.x, cv.x, acc);
        acc = fmaf(av.y, cv.y, acc);
        acc = fmaf(av.z, cv.z, acc);
        acc = fmaf(av.w, cv.w, acc);
    }
    W16[(size_t)i * N_FEAT + j] = (i == j) ? (unsigned short)0 : bf16_rne(0.5f * acc);
}

// ---------------- Kernel 2: fused GEMM + quadratic-form epilogue ----------------
// grid: 512 blocks x 256 threads (4 waves). Wave w: wm=w&1 (32 rows), wn=w>>1 (64 cols).
// As[r][c-chunk q] holds global chunk q^(r&7)  (16B chunks, swizzle kills bank conflicts).
__global__ __launch_bounds__(256, 2) void ffm_fused(const float* __restrict__ X,
                                                    const unsigned short* __restrict__ W16,
                                                    const float* __restrict__ w1,
                                                    const float* __restrict__ bvec,
                                                    float* __restrict__ out) {
    __shared__ __align__(16) unsigned short As[BM * N_FEAT];  // 64 KB, full-K X tile
    __shared__ __align__(16) unsigned short Bs[128 * BK];     // 16 KB, W16 tile
    float* part = (float*)Bs;                                 // aliases dead Bs at end

    const int tid  = threadIdx.x;
    const int lane = tid & 63;
    const int wave = tid >> 6;
    const int wm = wave & 1;
    const int wn = wave >> 1;
    const int quad = lane >> 4;
    const int l16  = lane & 15;

    const size_t row0 = (size_t)blockIdx.x * BM;

    // ---- Phase A: stage As = bf16(X[row0 : row0+64][0:512]), swizzled ----
    {
        const float4* X4 = (const float4*)(X + row0 * N_FEAT);
        for (int u = 0; u < 16; ++u) {
            const int g  = u * 256 + tid;
            const int r  = g >> 6;          // 0..63
            const int cc = g & 63;          // 16B chunk in row
            float4 f0 = X4[r * 128 + cc * 2];
            float4 f1 = X4[r * 128 + cc * 2 + 1];
            union { unsigned short us[8]; short8 v; } pk;
            pk.us[0] = bf16_rne(f0.x);
            pk.us[1] = bf16_rne(f0.y);
            pk.us[2] = bf16_rne(f0.z);
            pk.us[3] = bf16_rne(f0.w);
            pk.us[4] = bf16_rne(f1.x);
            pk.us[5] = bf16_rne(f1.y);
            pk.us[6] = bf16_rne(f1.z);
            pk.us[7] = bf16_rne(f1.w);
            *(short8*)(As + r * N_FEAT + ((cc ^ (r & 7)) << 3)) = pk.v;
        }
    }

    // Bs staging coords (XOR preimage so LDS dest stays lane-contiguous).
    const int srow = lane >> 3;
    const int scol = (((lane & 7) ^ srow) << 3);
    const int aswz = l16 & 7;

    float rs[2][4];
#pragma unroll
    for (int mi = 0; mi < 2; ++mi)
#pragma unroll
        for (int reg = 0; reg < 4; ++reg) rs[mi][reg] = 0.f;

    for (int cb = 0; cb < 4; ++cb) {
        const int col0 = cb * 128;

        f32x4 acc[2][4];
#pragma unroll
        for (int mi = 0; mi < 2; ++mi)
#pragma unroll
            for (int ni = 0; ni < 4; ++ni)
                acc[mi][ni] = (f32x4){0.f, 0.f, 0.f, 0.f};

        for (int k0 = 0; k0 < N_FEAT; k0 += BK) {
            __syncthreads();   // Bs safe to overwrite (also covers Phase A on iter 0)
#pragma unroll
            for (int c = 0; c < 4; ++c) {
                const int chunk = wave * 4 + c;          // 0..15, 1 KB each
                const int r = chunk * 8 + srow;          // Bs row 0..127
                async_copy16(W16 + (size_t)(col0 + r) * N_FEAT + k0 + scol,
                             Bs + chunk * 512);
            }
            __syncthreads();   // drain staging

#pragma unroll
            for (int kk = 0; kk < 2; ++kk) {
                short8 a[2], b[4];
                const int kc = (k0 >> 3) + kk * 4 + quad;     // global 16B-chunk idx
#pragma unroll
                for (int mi = 0; mi < 2; ++mi) {
                    const int ar = wm * 32 + mi * 16 + l16;   // ar&7 == l16&7
                    a[mi] = *(const short8*)(As + ar * N_FEAT + ((kc ^ aswz) << 3));
                }
                const int swc = ((kk * 4 + quad) ^ aswz) << 3;
#pragma unroll
                for (int ni = 0; ni < 4; ++ni) {
                    const int br = wn * 64 + ni * 16 + l16;
                    b[ni] = *(const short8*)(Bs + br * BK + swc);
                }
#pragma unroll
                for (int mi = 0; mi < 2; ++mi)
#pragma unroll
                    for (int ni = 0; ni < 4; ++ni)
                        acc[mi][ni] = __builtin_amdgcn_mfma_f32_16x16x32_bf16(
                            a[mi], b[ni], acc[mi][ni], 0, 0, 0);
            }
        }

        // Epilogue for this col-block: rs += x_hat * (y + w1), x_hat from As (swizzled).
        float w1v[4];
#pragma unroll
        for (int ni = 0; ni < 4; ++ni)
            w1v[ni] = w1[col0 + wn * 64 + ni * 16 + l16];
#pragma unroll
        for (int mi = 0; mi < 2; ++mi) {
#pragma unroll
            for (int ni = 0; ni < 4; ++ni) {
                const int gc = col0 + wn * 64 + ni * 16 + l16;   // elem idx in K
#pragma unroll
                for (int reg = 0; reg < 4; ++reg) {
                    const int row = wm * 32 + mi * 16 + quad * 4 + reg;
                    const int adr = row * N_FEAT + ((((gc >> 3) ^ (row & 7)) << 3) | (gc & 7));
                    const float xf = bf16_to_f(As[adr]);
                    rs[mi][reg] = fmaf(xf, acc[mi][ni][reg] + w1v[ni], rs[mi][reg]);
                }
            }
        }
    }

    __syncthreads();   // all Bs reads done before part[] aliases it

    // Reduce over l16, combine wn halves, bias + sigmoid.
#pragma unroll
    for (int mi = 0; mi < 2; ++mi)
#pragma unroll
        for (int reg = 0; reg < 4; ++reg) {
            float r = rs[mi][reg];
#pragma unroll
            for (int off = 1; off < 16; off <<= 1)
                r += __shfl_xor(r, off, 16);
            if (l16 == 0)
                part[wn * BM + wm * 32 + mi * 16 + quad * 4 + reg] = r;
        }
    __syncthreads();

    if (tid < BM) {
        const float t = part[tid] + part[BM + tid] + bvec[0];
        out[row0 + tid] = 1.0f / (1.0f + expf(-t));
    }
}

extern "C" void kernel_launch(void* const* d_in, const int* in_sizes, int n_in,
                              void* d_out, int out_size, void* d_ws, size_t ws_size,
                              hipStream_t stream) {
    const float* X   = (const float*)d_in[0];   // 32768 x 512
    const float* w1  = (const float*)d_in[1];   // 512
    const float* b   = (const float*)d_in[2];   // 1
    const float* v   = (const float*)d_in[3];   // 512 x 30 x 40
    const int*   f2f = (const int*)d_in[4];     // 512
    float* out = (float*)d_out;                 // 32768

    unsigned short* W16 = (unsigned short*)d_ws;   // 512 KB scratch

    build_w16<<<dim3(2, N_FEAT), 256, 0, stream>>>(v, f2f, W16);
    ffm_fused<<<B_ROWS / BM, 256, 0, stream>>>(X, W16, w1, b, out);
}